// Round 7
// baseline (118.487 us; speedup 1.0000x reference)
//
#include <hip/hip_runtime.h>

// ---------------------------------------------------------------------------
// DSTDGC R7.
// k0: per (n,t) tile; all global loads issued to raw regs BEFORE cvt; LDS-
//     staged coalesced stores.  (R6 k0, unchanged.)
// k12: fused adj+PV, SINGLE-PASS full-t adjs (R5-proven ordering).  tanh
//     fragments computed once into 64 VGPRs; m2s/m1s staged in a UNION with
//     adjs (dead after tanh->regs) so LDS = 75 KB -> 2 blocks/CU.
//     Every union reuse is barrier-separated:
//       stage -> bar -> tanh->regs -> bar -> phaseA(writes adjs) -> bar -> phaseB
// ---------------------------------------------------------------------------

typedef float  f32x4  __attribute__((ext_vector_type(4)));
typedef short  bf16x8 __attribute__((ext_vector_type(8)));
typedef short  bf16x4 __attribute__((ext_vector_type(4)));

static __device__ __forceinline__ short f2bf(float f) {
    unsigned u = __float_as_uint(f);
    unsigned r = (u + 0x7FFFu + ((u >> 16) & 1u)) >> 16;   // RNE
    return (short)r;
}

static __device__ __forceinline__ bf16x8 cvt8f(const float4 a, const float4 b) {
    bf16x8 r;
    r[0] = f2bf(a.x); r[1] = f2bf(a.y); r[2] = f2bf(a.z); r[3] = f2bf(a.w);
    r[4] = f2bf(b.x); r[5] = f2bf(b.y); r[6] = f2bf(b.z); r[7] = f2bf(b.w);
    return r;
}

static __device__ __forceinline__ bf16x8 cvt8(const float* p) {
    return cvt8f(*(const float4*)p, *(const float4*)(p + 4));
}

// tanh(x) = 1 - 2/(exp(2x)+1)
static __device__ __forceinline__ float tanh_fast(float x) {
    float e = __expf(2.0f * x);
    return 1.0f - 2.0f * __builtin_amdgcn_rcpf(e + 1.0f);
}

#define MFMA16(a, b, c) __builtin_amdgcn_mfma_f32_16x16x32_bf16((a), (b), (c), 0, 0, 0)

// ---------------------------------------------------------------------------
// K0: per (n,t).  xfT[n,t,o,v] bf16 ; m1g/m2g[n][k][i] f32.
// ---------------------------------------------------------------------------
__global__ __launch_bounds__(256, 3) void k0_proj(
    const float* __restrict__ x,
    const float* __restrict__ w_f,  const float* __restrict__ b_f,
    const float* __restrict__ w_m1, const float* __restrict__ b_m1,
    const float* __restrict__ w_m2, const float* __restrict__ b_m2,
    short* __restrict__ xfT, float* __restrict__ m1g, float* __restrict__ m2g)
{
    __shared__ short xfs[64 * 72];      // [o][v] bf16, padded
    __shared__ float ms[4 * 64];        // [r'][v]

    const int b   = blockIdx.x;         // n*64 + t
    const int n   = b >> 6;
    const int t   = b & 63;
    const int tid = threadIdx.x;
    const int l = tid & 63, w = tid >> 6;
    const int lr = l & 15, lg = l >> 4;
    const float* xt = x + ((size_t)b << 12);

    // ---- issue ALL loads first (raw f32), convert later: one vmcnt drain.
    float4 wr[2][2];
#pragma unroll
    for (int ks = 0; ks < 2; ++ks) {
        const float* p = w_f + (w * 16 + lr) * 64 + ks * 32 + lg * 8;
        wr[ks][0] = *(const float4*)p;
        wr[ks][1] = *(const float4*)(p + 4);
    }
    float4 z4 = {0.f, 0.f, 0.f, 0.f};
    float4 wm[2][2] = {{z4, z4}, {z4, z4}};
    if (w == 0 && lr < 4) {
        const float* wp = (lr < 2) ? (w_m1 + lr * 64) : (w_m2 + (lr - 2) * 64);
#pragma unroll
        for (int ks = 0; ks < 2; ++ks) {
            wm[ks][0] = *(const float4*)(wp + ks * 32 + lg * 8);
            wm[ks][1] = *(const float4*)(wp + ks * 32 + lg * 8 + 4);
        }
    }
    float4 xr[16];
#pragma unroll
    for (int ks = 0; ks < 2; ++ks)
#pragma unroll
        for (int nt = 0; nt < 4; ++nt) {
            const float* p = xt + (nt * 16 + lr) * 64 + ks * 32 + lg * 8;
            xr[(ks * 4 + nt) * 2 + 0] = *(const float4*)p;
            xr[(ks * 4 + nt) * 2 + 1] = *(const float4*)(p + 4);
        }

    // ---- convert
    bf16x8 afr[2];
#pragma unroll
    for (int ks = 0; ks < 2; ++ks) afr[ks] = cvt8f(wr[ks][0], wr[ks][1]);
    bf16x8 bfrag[2][4];
#pragma unroll
    for (int ks = 0; ks < 2; ++ks)
#pragma unroll
        for (int nt = 0; nt < 4; ++nt)
            bfrag[ks][nt] = cvt8f(xr[(ks * 4 + nt) * 2], xr[(ks * 4 + nt) * 2 + 1]);

    // ---- xf tile
    {
        f32x4 acc[4];
#pragma unroll
        for (int nt = 0; nt < 4; ++nt) acc[nt] = (f32x4){0.f, 0.f, 0.f, 0.f};
#pragma unroll
        for (int ks = 0; ks < 2; ++ks)
#pragma unroll
            for (int nt = 0; nt < 4; ++nt)
                acc[nt] = MFMA16(afr[ks], bfrag[ks][nt], acc[nt]);
#pragma unroll
        for (int e = 0; e < 4; ++e) {
            int o = w * 16 + lg * 4 + e;
            float bo = b_f[o];
#pragma unroll
            for (int nt = 0; nt < 4; ++nt)
                xfs[o * 72 + nt * 16 + lr] = f2bf(acc[nt][e] + bo);
        }
    }
    // ---- m1/m2 projections (wave 0)
    if (w == 0) {
        bf16x8 amf[2];
#pragma unroll
        for (int ks = 0; ks < 2; ++ks) amf[ks] = cvt8f(wm[ks][0], wm[ks][1]);
        f32x4 acc2[4];
#pragma unroll
        for (int nt = 0; nt < 4; ++nt) acc2[nt] = (f32x4){0.f, 0.f, 0.f, 0.f};
#pragma unroll
        for (int ks = 0; ks < 2; ++ks)
#pragma unroll
            for (int nt = 0; nt < 4; ++nt)
                acc2[nt] = MFMA16(amf[ks], bfrag[ks][nt], acc2[nt]);
        if (lg == 0) {
#pragma unroll
            for (int e = 0; e < 4; ++e)
#pragma unroll
                for (int nt = 0; nt < 4; ++nt)
                    ms[e * 64 + nt * 16 + lr] = acc2[nt][e];
        }
    }
    __syncthreads();

    // ---- coalesced stores
    short* xo = xfT + ((size_t)b << 12);
#pragma unroll
    for (int pass = 0; pass < 2; ++pass) {
        int row = ((pass << 8) + tid) >> 3;
        int v0  = (tid & 7) * 8;
        *(bf16x8*)(xo + row * 64 + v0) = *(const bf16x8*)(xfs + row * 72 + v0);
    }
    if (tid < 64) {
        int rp = tid >> 4;
        int q  = (tid & 15) * 4;
        float4 vq = *(const float4*)(ms + rp * 64 + q);
        float bias = (rp < 2) ? b_m1[rp] : b_m2[rp - 2];
        vq.x += bias; vq.y += bias; vq.z += bias; vq.w += bias;
        float* dst = ((rp < 2) ? m1g : m2g)
                   + n * 8192 + ((rp & 1) * 64 + t) * 64 + q;   // [n][k][i]
        *(float4*)dst = vq;
    }
}

// ---------------------------------------------------------------------------
// K12: fused adj + PV, single-pass full-t adjs, union'd LDS (75 KB).
// ---------------------------------------------------------------------------
__global__ __launch_bounds__(512, 4) void k12_adj_out(
    const float* __restrict__ Ast,
    const float* __restrict__ w_rm, const float* __restrict__ b_rm,
    const float* __restrict__ m1g,  const float* __restrict__ m2g,
    const int* __restrict__ alpha_p,
    const short* __restrict__ xfT, float* __restrict__ out)
{
    __shared__ union {
        struct {
            float m2s[128 * 66];        // [k][j] stride 66   (33.8 KB)
            float m1s[8 * 136];         // [iq][k]             (4.3 KB)
        } s;
        short adjs[64 * 584 + 1024];    // [t][i][j]          (75.0 KB)
    } u;

    const int wg = blockIdx.x;          // XCD swizzle: same-n -> same XCD
    const int n  = (wg & 7) + ((wg >> 6) << 3);
    const int i0 = ((wg >> 3) & 7) * 8;
    const int tid = threadIdx.x;

    // ---- stage m2[n]: [k][j] (float2 writes, ~2-way banks); m1 rows i0..i0+7
    {
        const float4* src2 = (const float4*)(m2g + n * 8192);
        for (int it = tid; it < 2048; it += 512) {
            int k = it >> 4, j0 = (it & 15) * 4;
            float4 v = src2[it];
            float* d = u.s.m2s + k * 66 + j0;
            *(float2*)d       = make_float2(v.x, v.y);
            *(float2*)(d + 2) = make_float2(v.z, v.w);
        }
    }
    if (tid < 256) {
        int k = tid & 127, half = tid >> 7;
        float4 v = *(const float4*)(m1g + n * 8192 + k * 64 + i0 + half * 4);
        u.s.m1s[(half * 4 + 0) * 136 + k] = v.x;
        u.s.m1s[(half * 4 + 1) * 136 + k] = v.y;
        u.s.m1s[(half * 4 + 2) * 136 + k] = v.z;
        u.s.m1s[(half * 4 + 3) * 136 + k] = v.w;
    }
    __syncthreads();

    const int l = tid & 63, w = tid >> 6;
    const int lr = l & 15, lg = l >> 4;
    const int ig = i0 + w;

    float alpha;
    {
        int raw = alpha_p[0];
        unsigned ur = (unsigned)(raw < 0 ? -raw : raw);
        alpha = (ur < (1u << 23)) ? (float)raw : __int_as_float(raw);
    }

    // ---- tanh fragments for ALL k, this wave's i, all j: computed ONCE
    bf16x8 bfr[4][4];                   // [jt][kt], 64 VGPR
    {
        const float* m1row = u.s.m1s + w * 136;
#pragma unroll
        for (int jt = 0; jt < 4; ++jt) {
            const int j = jt * 16 + lr;
#pragma unroll
            for (int kt = 0; kt < 4; ++kt) {
                const int k0 = kt * 32 + lg * 8;
#pragma unroll
                for (int d = 0; d < 8; ++d)
                    bfr[jt][kt][d] =
                        f2bf(tanh_fast(m1row[k0 + d] - u.s.m2s[(k0 + d) * 66 + j]));
            }
        }
    }
    __syncthreads();                    // m2s/m1s dead; adjs may now overwrite

    // ---- Phase A: adj for ALL t (4 quarters), this wave's i -> adjs LDS
#pragma unroll 1
    for (int q = 0; q < 4; ++q) {
        const int tq = q * 16 + lr;     // global t (column of D)
        bf16x8 afq[4];
#pragma unroll
        for (int kt = 0; kt < 4; ++kt)
            afq[kt] = cvt8(w_rm + tq * 128 + kt * 32 + lg * 8);
        const float brm = b_rm[tq];
#pragma unroll
        for (int jt = 0; jt < 4; ++jt) {
            f32x4 acc = (f32x4){0.f, 0.f, 0.f, 0.f};
#pragma unroll
            for (int kt = 0; kt < 4; ++kt)
                acc = MFMA16(bfr[jt][kt], afq[kt], acc);        // D[j][t]
            const int j0 = jt * 16 + lg * 4;
            float4 av = *(const float4*)(Ast + (tq << 12) + (ig << 6) + j0);
            bf16x4 pv;
            pv[0] = f2bf(alpha * (acc[0] + brm) + av.x);
            pv[1] = f2bf(alpha * (acc[1] + brm) + av.y);
            pv[2] = f2bf(alpha * (acc[2] + brm) + av.z);
            pv[3] = f2bf(alpha * (acc[3] + brm) + av.w);
            *(bf16x4*)(u.adjs + tq * 584 + w * 72 + j0) = pv;   // 8B ds_write
        }
    }
    __syncthreads();

    // ---- Phase B: wave w -> t = w*8 .. w*8+7
    const short* xn = xfT + ((size_t)n << 18);
    float*       on = out + ((size_t)n << 18);
#pragma unroll 2
    for (int tl = 0; tl < 8; ++tl) {
        const int t = w * 8 + tl;
        const short* xa = xn + ((size_t)t << 12);

        f32x4 acc2[4];
#pragma unroll
        for (int mt = 0; mt < 4; ++mt) acc2[mt] = (f32x4){0.f, 0.f, 0.f, 0.f};
#pragma unroll
        for (int ks = 0; ks < 2; ++ks) {
            bf16x8 bv = *(const bf16x8*)(u.adjs + t * 584 + lr * 72
                                         + ks * 32 + lg * 8);
#pragma unroll
            for (int mt = 0; mt < 4; ++mt) {
                bf16x8 af = *(const bf16x8*)(xa + (mt * 16 + lr) * 64
                                             + ks * 32 + lg * 8);
                acc2[mt] = MFMA16(af, bv, acc2[mt]);            // D[o][i]
            }
        }
        if (lr < 8) {                   // valid i columns only
            float* ob = on + ((size_t)t << 12) + (size_t)(i0 + lr) * 64;
#pragma unroll
            for (int mt = 0; mt < 4; ++mt)
                *(f32x4*)(ob + mt * 16 + lg * 4) = acc2[mt];    // 16B store
        }
    }
}

// ---------------------------------------------------------------------------
extern "C" void kernel_launch(void* const* d_in, const int* in_sizes, int n_in,
                              void* d_out, int out_size, void* d_ws, size_t ws_size,
                              hipStream_t stream)
{
    const float* x    = (const float*)d_in[0];
    const float* A    = (const float*)d_in[1];
    const float* w_m1 = (const float*)d_in[2];
    const float* b_m1 = (const float*)d_in[3];
    const float* w_m2 = (const float*)d_in[4];
    const float* b_m2 = (const float*)d_in[5];
    const float* w_rm = (const float*)d_in[6];
    const float* b_rm = (const float*)d_in[7];
    const float* w_f  = (const float*)d_in[8];
    const float* b_f  = (const float*)d_in[9];
    const int*   alpha = (const int*)d_in[10];

    char* ws = (char*)d_ws;
    float* m1g = (float*)(ws);                              // 2 MB  [n][k][i]
    float* m2g = (float*)(ws + (size_t)2 * 1024 * 1024);    // 2 MB  [n][k][j]
    short* xfT = (short*)(ws + (size_t)4 * 1024 * 1024);    // 32 MB [n][t][o][v]
    float* out = (float*)d_out;

    k0_proj<<<dim3(4096), dim3(256), 0, stream>>>(x, w_f, b_f, w_m1, b_m1,
                                                  w_m2, b_m2, xfT, m1g, m2g);
    k12_adj_out<<<dim3(512), dim3(512), 0, stream>>>(A, w_rm, b_rm, m1g, m2g,
                                                     alpha, xfT, out);
}

// Round 8
// 114.319 us; speedup vs baseline: 1.0365x; 1.0365x over previous
//
#include <hip/hip_runtime.h>

// ---------------------------------------------------------------------------
// DSTDGC R8.
// k0: per (n,t) tile; all global loads issued to raw regs BEFORE cvt; LDS-
//     staged coalesced stores.  (unchanged from R7)
// k12: R7 structure (single-pass full-t adjs, union'd LDS 75 KB -> 2 blk/CU,
//     register-resident tanh fragments) with __launch_bounds__(512) — the
//     (512,4) clamp made the compiler allocate 64 VGPR and spill bfr[4][4]
//     to scratch (WRITE_SIZE 114.7 MB vs 67 expected).  128 VGPR still
//     allows 4 waves/SIMD with both LDS blocks resident.
// ---------------------------------------------------------------------------

typedef float  f32x4  __attribute__((ext_vector_type(4)));
typedef short  bf16x8 __attribute__((ext_vector_type(8)));
typedef short  bf16x4 __attribute__((ext_vector_type(4)));

static __device__ __forceinline__ short f2bf(float f) {
    unsigned u = __float_as_uint(f);
    unsigned r = (u + 0x7FFFu + ((u >> 16) & 1u)) >> 16;   // RNE
    return (short)r;
}

static __device__ __forceinline__ bf16x8 cvt8f(const float4 a, const float4 b) {
    bf16x8 r;
    r[0] = f2bf(a.x); r[1] = f2bf(a.y); r[2] = f2bf(a.z); r[3] = f2bf(a.w);
    r[4] = f2bf(b.x); r[5] = f2bf(b.y); r[6] = f2bf(b.z); r[7] = f2bf(b.w);
    return r;
}

static __device__ __forceinline__ bf16x8 cvt8(const float* p) {
    return cvt8f(*(const float4*)p, *(const float4*)(p + 4));
}

// tanh(x) = 1 - 2/(exp(2x)+1)
static __device__ __forceinline__ float tanh_fast(float x) {
    float e = __expf(2.0f * x);
    return 1.0f - 2.0f * __builtin_amdgcn_rcpf(e + 1.0f);
}

#define MFMA16(a, b, c) __builtin_amdgcn_mfma_f32_16x16x32_bf16((a), (b), (c), 0, 0, 0)

// ---------------------------------------------------------------------------
// K0: per (n,t).  xfT[n,t,o,v] bf16 ; m1g/m2g[n][k][i] f32.
// ---------------------------------------------------------------------------
__global__ __launch_bounds__(256, 3) void k0_proj(
    const float* __restrict__ x,
    const float* __restrict__ w_f,  const float* __restrict__ b_f,
    const float* __restrict__ w_m1, const float* __restrict__ b_m1,
    const float* __restrict__ w_m2, const float* __restrict__ b_m2,
    short* __restrict__ xfT, float* __restrict__ m1g, float* __restrict__ m2g)
{
    __shared__ short xfs[64 * 72];      // [o][v] bf16, padded
    __shared__ float ms[4 * 64];        // [r'][v]

    const int b   = blockIdx.x;         // n*64 + t
    const int n   = b >> 6;
    const int t   = b & 63;
    const int tid = threadIdx.x;
    const int l = tid & 63, w = tid >> 6;
    const int lr = l & 15, lg = l >> 4;
    const float* xt = x + ((size_t)b << 12);

    // ---- issue ALL loads first (raw f32), convert later: one vmcnt drain.
    float4 wr[2][2];
#pragma unroll
    for (int ks = 0; ks < 2; ++ks) {
        const float* p = w_f + (w * 16 + lr) * 64 + ks * 32 + lg * 8;
        wr[ks][0] = *(const float4*)p;
        wr[ks][1] = *(const float4*)(p + 4);
    }
    float4 z4 = {0.f, 0.f, 0.f, 0.f};
    float4 wm[2][2] = {{z4, z4}, {z4, z4}};
    if (w == 0 && lr < 4) {
        const float* wp = (lr < 2) ? (w_m1 + lr * 64) : (w_m2 + (lr - 2) * 64);
#pragma unroll
        for (int ks = 0; ks < 2; ++ks) {
            wm[ks][0] = *(const float4*)(wp + ks * 32 + lg * 8);
            wm[ks][1] = *(const float4*)(wp + ks * 32 + lg * 8 + 4);
        }
    }
    float4 xr[16];
#pragma unroll
    for (int ks = 0; ks < 2; ++ks)
#pragma unroll
        for (int nt = 0; nt < 4; ++nt) {
            const float* p = xt + (nt * 16 + lr) * 64 + ks * 32 + lg * 8;
            xr[(ks * 4 + nt) * 2 + 0] = *(const float4*)p;
            xr[(ks * 4 + nt) * 2 + 1] = *(const float4*)(p + 4);
        }

    // ---- convert
    bf16x8 afr[2];
#pragma unroll
    for (int ks = 0; ks < 2; ++ks) afr[ks] = cvt8f(wr[ks][0], wr[ks][1]);
    bf16x8 bfrag[2][4];
#pragma unroll
    for (int ks = 0; ks < 2; ++ks)
#pragma unroll
        for (int nt = 0; nt < 4; ++nt)
            bfrag[ks][nt] = cvt8f(xr[(ks * 4 + nt) * 2], xr[(ks * 4 + nt) * 2 + 1]);

    // ---- xf tile
    {
        f32x4 acc[4];
#pragma unroll
        for (int nt = 0; nt < 4; ++nt) acc[nt] = (f32x4){0.f, 0.f, 0.f, 0.f};
#pragma unroll
        for (int ks = 0; ks < 2; ++ks)
#pragma unroll
            for (int nt = 0; nt < 4; ++nt)
                acc[nt] = MFMA16(afr[ks], bfrag[ks][nt], acc[nt]);
#pragma unroll
        for (int e = 0; e < 4; ++e) {
            int o = w * 16 + lg * 4 + e;
            float bo = b_f[o];
#pragma unroll
            for (int nt = 0; nt < 4; ++nt)
                xfs[o * 72 + nt * 16 + lr] = f2bf(acc[nt][e] + bo);
        }
    }
    // ---- m1/m2 projections (wave 0)
    if (w == 0) {
        bf16x8 amf[2];
#pragma unroll
        for (int ks = 0; ks < 2; ++ks) amf[ks] = cvt8f(wm[ks][0], wm[ks][1]);
        f32x4 acc2[4];
#pragma unroll
        for (int nt = 0; nt < 4; ++nt) acc2[nt] = (f32x4){0.f, 0.f, 0.f, 0.f};
#pragma unroll
        for (int ks = 0; ks < 2; ++ks)
#pragma unroll
            for (int nt = 0; nt < 4; ++nt)
                acc2[nt] = MFMA16(amf[ks], bfrag[ks][nt], acc2[nt]);
        if (lg == 0) {
#pragma unroll
            for (int e = 0; e < 4; ++e)
#pragma unroll
                for (int nt = 0; nt < 4; ++nt)
                    ms[e * 64 + nt * 16 + lr] = acc2[nt][e];
        }
    }
    __syncthreads();

    // ---- coalesced stores
    short* xo = xfT + ((size_t)b << 12);
#pragma unroll
    for (int pass = 0; pass < 2; ++pass) {
        int row = ((pass << 8) + tid) >> 3;
        int v0  = (tid & 7) * 8;
        *(bf16x8*)(xo + row * 64 + v0) = *(const bf16x8*)(xfs + row * 72 + v0);
    }
    if (tid < 64) {
        int rp = tid >> 4;
        int q  = (tid & 15) * 4;
        float4 vq = *(const float4*)(ms + rp * 64 + q);
        float bias = (rp < 2) ? b_m1[rp] : b_m2[rp - 2];
        vq.x += bias; vq.y += bias; vq.z += bias; vq.w += bias;
        float* dst = ((rp < 2) ? m1g : m2g)
                   + n * 8192 + ((rp & 1) * 64 + t) * 64 + q;   // [n][k][i]
        *(float4*)dst = vq;
    }
}

// ---------------------------------------------------------------------------
// K12: fused adj + PV, single-pass full-t adjs, union'd LDS (75 KB).
// ---------------------------------------------------------------------------
__global__ __launch_bounds__(512) void k12_adj_out(
    const float* __restrict__ Ast,
    const float* __restrict__ w_rm, const float* __restrict__ b_rm,
    const float* __restrict__ m1g,  const float* __restrict__ m2g,
    const int* __restrict__ alpha_p,
    const short* __restrict__ xfT, float* __restrict__ out)
{
    __shared__ union {
        struct {
            float m2s[128 * 66];        // [k][j] stride 66   (33.8 KB)
            float m1s[8 * 136];         // [iq][k]             (4.3 KB)
        } s;
        short adjs[64 * 584 + 1024];    // [t][i][j]          (75.0 KB)
    } u;

    const int wg = blockIdx.x;          // XCD swizzle: same-n -> same XCD
    const int n  = (wg & 7) + ((wg >> 6) << 3);
    const int i0 = ((wg >> 3) & 7) * 8;
    const int tid = threadIdx.x;

    // ---- stage m2[n]: [k][j] (float2 writes, ~2-way banks); m1 rows i0..i0+7
    {
        const float4* src2 = (const float4*)(m2g + n * 8192);
        for (int it = tid; it < 2048; it += 512) {
            int k = it >> 4, j0 = (it & 15) * 4;
            float4 v = src2[it];
            float* d = u.s.m2s + k * 66 + j0;
            *(float2*)d       = make_float2(v.x, v.y);
            *(float2*)(d + 2) = make_float2(v.z, v.w);
        }
    }
    if (tid < 256) {
        int k = tid & 127, half = tid >> 7;
        float4 v = *(const float4*)(m1g + n * 8192 + k * 64 + i0 + half * 4);
        u.s.m1s[(half * 4 + 0) * 136 + k] = v.x;
        u.s.m1s[(half * 4 + 1) * 136 + k] = v.y;
        u.s.m1s[(half * 4 + 2) * 136 + k] = v.z;
        u.s.m1s[(half * 4 + 3) * 136 + k] = v.w;
    }
    __syncthreads();

    const int l = tid & 63, w = tid >> 6;
    const int lr = l & 15, lg = l >> 4;
    const int ig = i0 + w;

    float alpha;
    {
        int raw = alpha_p[0];
        unsigned ur = (unsigned)(raw < 0 ? -raw : raw);
        alpha = (ur < (1u << 23)) ? (float)raw : __int_as_float(raw);
    }

    // ---- tanh fragments for ALL k, this wave's i, all j: computed ONCE
    bf16x8 bfr[4][4];                   // [jt][kt], 64 VGPR
    {
        const float* m1row = u.s.m1s + w * 136;
#pragma unroll
        for (int jt = 0; jt < 4; ++jt) {
            const int j = jt * 16 + lr;
#pragma unroll
            for (int kt = 0; kt < 4; ++kt) {
                const int k0 = kt * 32 + lg * 8;
#pragma unroll
                for (int d = 0; d < 8; ++d)
                    bfr[jt][kt][d] =
                        f2bf(tanh_fast(m1row[k0 + d] - u.s.m2s[(k0 + d) * 66 + j]));
            }
        }
    }
    __syncthreads();                    // m2s/m1s dead; adjs may now overwrite

    // ---- Phase A: adj for ALL t (4 quarters), this wave's i -> adjs LDS
#pragma unroll 1
    for (int q = 0; q < 4; ++q) {
        const int tq = q * 16 + lr;     // global t (column of D)
        bf16x8 afq[4];
#pragma unroll
        for (int kt = 0; kt < 4; ++kt)
            afq[kt] = cvt8(w_rm + tq * 128 + kt * 32 + lg * 8);
        const float brm = b_rm[tq];
#pragma unroll
        for (int jt = 0; jt < 4; ++jt) {
            f32x4 acc = (f32x4){0.f, 0.f, 0.f, 0.f};
#pragma unroll
            for (int kt = 0; kt < 4; ++kt)
                acc = MFMA16(bfr[jt][kt], afq[kt], acc);        // D[j][t]
            const int j0 = jt * 16 + lg * 4;
            float4 av = *(const float4*)(Ast + (tq << 12) + (ig << 6) + j0);
            bf16x4 pv;
            pv[0] = f2bf(alpha * (acc[0] + brm) + av.x);
            pv[1] = f2bf(alpha * (acc[1] + brm) + av.y);
            pv[2] = f2bf(alpha * (acc[2] + brm) + av.z);
            pv[3] = f2bf(alpha * (acc[3] + brm) + av.w);
            *(bf16x4*)(u.adjs + tq * 584 + w * 72 + j0) = pv;   // 8B ds_write
        }
    }
    __syncthreads();

    // ---- Phase B: wave w -> t = w*8 .. w*8+7
    const short* xn = xfT + ((size_t)n << 18);
    float*       on = out + ((size_t)n << 18);
#pragma unroll 2
    for (int tl = 0; tl < 8; ++tl) {
        const int t = w * 8 + tl;
        const short* xa = xn + ((size_t)t << 12);

        f32x4 acc2[4];
#pragma unroll
        for (int mt = 0; mt < 4; ++mt) acc2[mt] = (f32x4){0.f, 0.f, 0.f, 0.f};
#pragma unroll
        for (int ks = 0; ks < 2; ++ks) {
            bf16x8 bv = *(const bf16x8*)(u.adjs + t * 584 + lr * 72
                                         + ks * 32 + lg * 8);
#pragma unroll
            for (int mt = 0; mt < 4; ++mt) {
                bf16x8 af = *(const bf16x8*)(xa + (mt * 16 + lr) * 64
                                             + ks * 32 + lg * 8);
                acc2[mt] = MFMA16(af, bv, acc2[mt]);            // D[o][i]
            }
        }
        if (lr < 8) {                   // valid i columns only
            float* ob = on + ((size_t)t << 12) + (size_t)(i0 + lr) * 64;
#pragma unroll
            for (int mt = 0; mt < 4; ++mt)
                *(f32x4*)(ob + mt * 16 + lg * 4) = acc2[mt];    // 16B store
        }
    }
}

// ---------------------------------------------------------------------------
extern "C" void kernel_launch(void* const* d_in, const int* in_sizes, int n_in,
                              void* d_out, int out_size, void* d_ws, size_t ws_size,
                              hipStream_t stream)
{
    const float* x    = (const float*)d_in[0];
    const float* A    = (const float*)d_in[1];
    const float* w_m1 = (const float*)d_in[2];
    const float* b_m1 = (const float*)d_in[3];
    const float* w_m2 = (const float*)d_in[4];
    const float* b_m2 = (const float*)d_in[5];
    const float* w_rm = (const float*)d_in[6];
    const float* b_rm = (const float*)d_in[7];
    const float* w_f  = (const float*)d_in[8];
    const float* b_f  = (const float*)d_in[9];
    const int*   alpha = (const int*)d_in[10];

    char* ws = (char*)d_ws;
    float* m1g = (float*)(ws);                              // 2 MB  [n][k][i]
    float* m2g = (float*)(ws + (size_t)2 * 1024 * 1024);    // 2 MB  [n][k][j]
    short* xfT = (short*)(ws + (size_t)4 * 1024 * 1024);    // 32 MB [n][t][o][v]
    float* out = (float*)d_out;

    k0_proj<<<dim3(4096), dim3(256), 0, stream>>>(x, w_f, b_f, w_m1, b_m1,
                                                  w_m2, b_m2, xfT, m1g, m2g);
    k12_adj_out<<<dim3(512), dim3(512), 0, stream>>>(A, w_rm, b_rm, m1g, m2g,
                                                     alpha, xfT, out);
}

// Round 9
// 112.145 us; speedup vs baseline: 1.0565x; 1.0194x over previous
//
#include <hip/hip_runtime.h>

// ---------------------------------------------------------------------------
// DSTDGC R9 — attribution round: k12 split at the adj boundary.
// k0: R8 shape, clamp removed (was (256,3) -> VGPR 60 -> serialized loads).
// k1: stage+tanh+adj -> adjf global bf16.  Transient bfr/afq (low VGPR),
//     38 KB LDS -> 2+ blocks/CU.  Coalesced-ish 8B stores (R4-proven layout).
// k2: PV per (n,t) wave (R4-proven), grid 1024 -> 4 block-rounds/CU.
// ---------------------------------------------------------------------------

typedef float  f32x4  __attribute__((ext_vector_type(4)));
typedef short  bf16x8 __attribute__((ext_vector_type(8)));
typedef short  bf16x4 __attribute__((ext_vector_type(4)));

static __device__ __forceinline__ short f2bf(float f) {
    unsigned u = __float_as_uint(f);
    unsigned r = (u + 0x7FFFu + ((u >> 16) & 1u)) >> 16;   // RNE
    return (short)r;
}

static __device__ __forceinline__ bf16x8 cvt8f(const float4 a, const float4 b) {
    bf16x8 r;
    r[0] = f2bf(a.x); r[1] = f2bf(a.y); r[2] = f2bf(a.z); r[3] = f2bf(a.w);
    r[4] = f2bf(b.x); r[5] = f2bf(b.y); r[6] = f2bf(b.z); r[7] = f2bf(b.w);
    return r;
}

static __device__ __forceinline__ bf16x8 cvt8(const float* p) {
    return cvt8f(*(const float4*)p, *(const float4*)(p + 4));
}

// tanh(x) = 1 - 2/(exp(2x)+1)
static __device__ __forceinline__ float tanh_fast(float x) {
    float e = __expf(2.0f * x);
    return 1.0f - 2.0f * __builtin_amdgcn_rcpf(e + 1.0f);
}

#define MFMA16(a, b, c) __builtin_amdgcn_mfma_f32_16x16x32_bf16((a), (b), (c), 0, 0, 0)

// ---------------------------------------------------------------------------
// K0: per (n,t).  xfT[n,t,o,v] bf16 ; m1g/m2g[n][k][i] f32.
// ---------------------------------------------------------------------------
__global__ __launch_bounds__(256) void k0_proj(
    const float* __restrict__ x,
    const float* __restrict__ w_f,  const float* __restrict__ b_f,
    const float* __restrict__ w_m1, const float* __restrict__ b_m1,
    const float* __restrict__ w_m2, const float* __restrict__ b_m2,
    short* __restrict__ xfT, float* __restrict__ m1g, float* __restrict__ m2g)
{
    __shared__ short xfs[64 * 72];      // [o][v] bf16, padded
    __shared__ float ms[4 * 64];        // [r'][v]

    const int b   = blockIdx.x;         // n*64 + t
    const int n   = b >> 6;
    const int t   = b & 63;
    const int tid = threadIdx.x;
    const int l = tid & 63, w = tid >> 6;
    const int lr = l & 15, lg = l >> 4;
    const float* xt = x + ((size_t)b << 12);

    // ---- issue ALL loads first (raw f32), convert later.
    float4 wr[2][2];
#pragma unroll
    for (int ks = 0; ks < 2; ++ks) {
        const float* p = w_f + (w * 16 + lr) * 64 + ks * 32 + lg * 8;
        wr[ks][0] = *(const float4*)p;
        wr[ks][1] = *(const float4*)(p + 4);
    }
    float4 z4 = {0.f, 0.f, 0.f, 0.f};
    float4 wm[2][2] = {{z4, z4}, {z4, z4}};
    if (w == 0 && lr < 4) {
        const float* wp = (lr < 2) ? (w_m1 + lr * 64) : (w_m2 + (lr - 2) * 64);
#pragma unroll
        for (int ks = 0; ks < 2; ++ks) {
            wm[ks][0] = *(const float4*)(wp + ks * 32 + lg * 8);
            wm[ks][1] = *(const float4*)(wp + ks * 32 + lg * 8 + 4);
        }
    }
    float4 xr[16];
#pragma unroll
    for (int ks = 0; ks < 2; ++ks)
#pragma unroll
        for (int nt = 0; nt < 4; ++nt) {
            const float* p = xt + (nt * 16 + lr) * 64 + ks * 32 + lg * 8;
            xr[(ks * 4 + nt) * 2 + 0] = *(const float4*)p;
            xr[(ks * 4 + nt) * 2 + 1] = *(const float4*)(p + 4);
        }

    // ---- convert
    bf16x8 afr[2];
#pragma unroll
    for (int ks = 0; ks < 2; ++ks) afr[ks] = cvt8f(wr[ks][0], wr[ks][1]);
    bf16x8 bfrag[2][4];
#pragma unroll
    for (int ks = 0; ks < 2; ++ks)
#pragma unroll
        for (int nt = 0; nt < 4; ++nt)
            bfrag[ks][nt] = cvt8f(xr[(ks * 4 + nt) * 2], xr[(ks * 4 + nt) * 2 + 1]);

    // ---- xf tile
    {
        f32x4 acc[4];
#pragma unroll
        for (int nt = 0; nt < 4; ++nt) acc[nt] = (f32x4){0.f, 0.f, 0.f, 0.f};
#pragma unroll
        for (int ks = 0; ks < 2; ++ks)
#pragma unroll
            for (int nt = 0; nt < 4; ++nt)
                acc[nt] = MFMA16(afr[ks], bfrag[ks][nt], acc[nt]);
#pragma unroll
        for (int e = 0; e < 4; ++e) {
            int o = w * 16 + lg * 4 + e;
            float bo = b_f[o];
#pragma unroll
            for (int nt = 0; nt < 4; ++nt)
                xfs[o * 72 + nt * 16 + lr] = f2bf(acc[nt][e] + bo);
        }
    }
    // ---- m1/m2 projections (wave 0)
    if (w == 0) {
        bf16x8 amf[2];
#pragma unroll
        for (int ks = 0; ks < 2; ++ks) amf[ks] = cvt8f(wm[ks][0], wm[ks][1]);
        f32x4 acc2[4];
#pragma unroll
        for (int nt = 0; nt < 4; ++nt) acc2[nt] = (f32x4){0.f, 0.f, 0.f, 0.f};
#pragma unroll
        for (int ks = 0; ks < 2; ++ks)
#pragma unroll
            for (int nt = 0; nt < 4; ++nt)
                acc2[nt] = MFMA16(amf[ks], bfrag[ks][nt], acc2[nt]);
        if (lg == 0) {
#pragma unroll
            for (int e = 0; e < 4; ++e)
#pragma unroll
                for (int nt = 0; nt < 4; ++nt)
                    ms[e * 64 + nt * 16 + lr] = acc2[nt][e];
        }
    }
    __syncthreads();

    // ---- coalesced stores
    short* xo = xfT + ((size_t)b << 12);
#pragma unroll
    for (int pass = 0; pass < 2; ++pass) {
        int row = ((pass << 8) + tid) >> 3;
        int v0  = (tid & 7) * 8;
        *(bf16x8*)(xo + row * 64 + v0) = *(const bf16x8*)(xfs + row * 72 + v0);
    }
    if (tid < 64) {
        int rp = tid >> 4;
        int q  = (tid & 15) * 4;
        float4 vq = *(const float4*)(ms + rp * 64 + q);
        float bias = (rp < 2) ? b_m1[rp] : b_m2[rp - 2];
        vq.x += bias; vq.y += bias; vq.z += bias; vq.w += bias;
        float* dst = ((rp < 2) ? m1g : m2g)
                   + n * 8192 + ((rp & 1) * 64 + t) * 64 + q;   // [n][k][i]
        *(float4*)dst = vq;
    }
}

// ---------------------------------------------------------------------------
// K1: block (n, i-chunk of 8), 512 thr.  adjf[n,t,i,j] bf16 to global.
//     Transient bfr (per jt) and afq (per q) keep VGPR ~90 -> 2 blocks/CU.
// ---------------------------------------------------------------------------
__global__ __launch_bounds__(512) void k1_adj(
    const float* __restrict__ Ast,
    const float* __restrict__ w_rm, const float* __restrict__ b_rm,
    const float* __restrict__ m1g,  const float* __restrict__ m2g,
    const int* __restrict__ alpha_p,
    short* __restrict__ adjf)
{
    __shared__ float m2s[128 * 66];     // [k][j] stride 66  (33.8 KB)
    __shared__ float m1s[8 * 136];      // [iq][k]            (4.3 KB)

    const int wg = blockIdx.x;          // XCD swizzle: same-n -> same XCD
    const int n  = (wg & 7) + ((wg >> 6) << 3);
    const int i0 = ((wg >> 3) & 7) * 8;
    const int tid = threadIdx.x;

    {
        const float4* src2 = (const float4*)(m2g + n * 8192);
        for (int it = tid; it < 2048; it += 512) {
            int k = it >> 4, j0 = (it & 15) * 4;
            float4 v = src2[it];
            float* d = m2s + k * 66 + j0;
            *(float2*)d       = make_float2(v.x, v.y);
            *(float2*)(d + 2) = make_float2(v.z, v.w);
        }
    }
    if (tid < 256) {
        int k = tid & 127, half = tid >> 7;
        float4 v = *(const float4*)(m1g + n * 8192 + k * 64 + i0 + half * 4);
        m1s[(half * 4 + 0) * 136 + k] = v.x;
        m1s[(half * 4 + 1) * 136 + k] = v.y;
        m1s[(half * 4 + 2) * 136 + k] = v.z;
        m1s[(half * 4 + 3) * 136 + k] = v.w;
    }
    __syncthreads();

    const int l = tid & 63, w = tid >> 6;
    const int lr = l & 15, lg = l >> 4;
    const int ig = i0 + w;

    float alpha;
    {
        int raw = alpha_p[0];
        unsigned ur = (unsigned)(raw < 0 ? -raw : raw);
        alpha = (ur < (1u << 23)) ? (float)raw : __int_as_float(raw);
    }

    const float* m1row = m1s + w * 136;
    short* adjb = adjf + ((size_t)n << 18) + (ig << 6);

#pragma unroll 1
    for (int jt = 0; jt < 4; ++jt) {
        const int j = jt * 16 + lr;
        bf16x8 bfr[4];                  // transient tanh A-fragments
#pragma unroll
        for (int kt = 0; kt < 4; ++kt) {
            const int k0 = kt * 32 + lg * 8;
#pragma unroll
            for (int d = 0; d < 8; ++d)
                bfr[kt][d] = f2bf(tanh_fast(m1row[k0 + d] - m2s[(k0 + d) * 66 + j]));
        }
        const int j0 = jt * 16 + lg * 4;
#pragma unroll
        for (int q = 0; q < 4; ++q) {
            const int tq = q * 16 + lr;
            bf16x8 afq[4];              // transient w_rm B-fragments
#pragma unroll
            for (int kt = 0; kt < 4; ++kt)
                afq[kt] = cvt8(w_rm + tq * 128 + kt * 32 + lg * 8);
            f32x4 acc = (f32x4){0.f, 0.f, 0.f, 0.f};
#pragma unroll
            for (int kt = 0; kt < 4; ++kt)
                acc = MFMA16(bfr[kt], afq[kt], acc);            // D[j][t]
            float4 av = *(const float4*)(Ast + (tq << 12) + (ig << 6) + j0);
            float brm = b_rm[tq];
            bf16x4 pv;
            pv[0] = f2bf(alpha * (acc[0] + brm) + av.x);
            pv[1] = f2bf(alpha * (acc[1] + brm) + av.y);
            pv[2] = f2bf(alpha * (acc[2] + brm) + av.z);
            pv[3] = f2bf(alpha * (acc[3] + brm) + av.w);
            *(bf16x4*)(adjb + ((size_t)tq << 12) + j0) = pv;    // 8B store
        }
    }
}

// ---------------------------------------------------------------------------
// K2: one wave per (n,t): out[i,o] = sum_j adj[i,j] xf[j,o].  D[o][i] ->
//     float4 stores.  Grid 1024 -> ~4 block-rounds/CU for pipelining.
// ---------------------------------------------------------------------------
__global__ __launch_bounds__(256) void k2_out(
    const short* __restrict__ adjf, const short* __restrict__ xfT,
    float* __restrict__ out)
{
    const int tid = threadIdx.x;
    const int l = tid & 63, w = tid >> 6;
    const int lr = l & 15, lg = l >> 4;
    const int pair = blockIdx.x * 4 + w;      // n*64 + t

    const short* Ab = xfT  + ((size_t)pair << 12);  // A: rows o, contig j
    const short* Bb = adjf + ((size_t)pair << 12);  // B: cols i, contig j
    float*       Ob = out  + ((size_t)pair << 12);

    bf16x8 af[4][2], bf[4][2];
#pragma unroll
    for (int mt = 0; mt < 4; ++mt)
#pragma unroll
        for (int ks = 0; ks < 2; ++ks)
            af[mt][ks] = *(const bf16x8*)(Ab + (mt * 16 + lr) * 64 + ks * 32 + lg * 8);
#pragma unroll
    for (int nt = 0; nt < 4; ++nt)
#pragma unroll
        for (int ks = 0; ks < 2; ++ks)
            bf[nt][ks] = *(const bf16x8*)(Bb + (nt * 16 + lr) * 64 + ks * 32 + lg * 8);

    f32x4 acc[4][4];
#pragma unroll
    for (int mt = 0; mt < 4; ++mt)
#pragma unroll
        for (int nt = 0; nt < 4; ++nt) acc[mt][nt] = (f32x4){0.f, 0.f, 0.f, 0.f};

#pragma unroll
    for (int ks = 0; ks < 2; ++ks)
#pragma unroll
        for (int mt = 0; mt < 4; ++mt)
#pragma unroll
            for (int nt = 0; nt < 4; ++nt)
                acc[mt][nt] = MFMA16(af[mt][ks], bf[nt][ks], acc[mt][nt]);

    // D[o][i]: lane i = nt*16+lr, o = mt*16+lg*4+e -> float4 stores
#pragma unroll
    for (int nt = 0; nt < 4; ++nt) {
        int i = nt * 16 + lr;
#pragma unroll
        for (int mt = 0; mt < 4; ++mt) {
            int o0 = mt * 16 + lg * 4;
            *(f32x4*)(Ob + i * 64 + o0) = acc[mt][nt];
        }
    }
}

// ---------------------------------------------------------------------------
extern "C" void kernel_launch(void* const* d_in, const int* in_sizes, int n_in,
                              void* d_out, int out_size, void* d_ws, size_t ws_size,
                              hipStream_t stream)
{
    const float* x    = (const float*)d_in[0];
    const float* A    = (const float*)d_in[1];
    const float* w_m1 = (const float*)d_in[2];
    const float* b_m1 = (const float*)d_in[3];
    const float* w_m2 = (const float*)d_in[4];
    const float* b_m2 = (const float*)d_in[5];
    const float* w_rm = (const float*)d_in[6];
    const float* b_rm = (const float*)d_in[7];
    const float* w_f  = (const float*)d_in[8];
    const float* b_f  = (const float*)d_in[9];
    const int*   alpha = (const int*)d_in[10];

    char* ws = (char*)d_ws;
    float* m1g = (float*)(ws);                              // 2 MB  [n][k][i]
    float* m2g = (float*)(ws + (size_t)2 * 1024 * 1024);    // 2 MB  [n][k][j]
    short* xfT = (short*)(ws + (size_t)4 * 1024 * 1024);    // 32 MB [n][t][o][v]
    short* adjf = (short*)(ws + (size_t)4 * 1024 * 1024 + (size_t)33554432);
    float* out = (float*)d_out;

    k0_proj<<<dim3(4096), dim3(256), 0, stream>>>(x, w_f, b_f, w_m1, b_m1,
                                                  w_m2, b_m2, xfT, m1g, m2g);
    k1_adj<<<dim3(512), dim3(512), 0, stream>>>(A, w_rm, b_rm, m1g, m2g,
                                                alpha, adjf);
    k2_out<<<dim3(1024), dim3(256), 0, stream>>>(adjf, xfT, out);
}

// Round 10
// 89.437 us; speedup vs baseline: 1.3248x; 1.2539x over previous
//
#include <hip/hip_runtime.h>

// ---------------------------------------------------------------------------
// DSTDGC R10.
// Identity used: out = adj @ (x W_f^T + b_f) = (adj @ x) W_f^T + rowsum(adj) b_f
// k0_stream: PURE STREAMING (no MFMA/LDS/barrier): x -> xbf (bf16 copy) and
//            m1g/m2g projections.  8 threads/row, 16B coalesced in+out,
//            shfl-reduce dots.  (k0's GEMM structure was VGPR-starved: the
//            compiler pinned 64 VGPR -> serial load batches -> 49 us.)
// k1: unchanged from R9 (stage m -> tanh -> MFMA -> adjf bf16).
// k2: per (n,t): P = adj @ x (xT staged in LDS; ones-col gives rowsum), then
//     out = W_aug @ P (b_f as constructed k=64 fragment).  float4 stores.
// ---------------------------------------------------------------------------

typedef float  f32x4  __attribute__((ext_vector_type(4)));
typedef short  bf16x8 __attribute__((ext_vector_type(8)));
typedef short  bf16x4 __attribute__((ext_vector_type(4)));

static __device__ __forceinline__ short f2bf(float f) {
    unsigned u = __float_as_uint(f);
    unsigned r = (u + 0x7FFFu + ((u >> 16) & 1u)) >> 16;   // RNE
    return (short)r;
}

static __device__ __forceinline__ bf16x8 cvt8f(const float4 a, const float4 b) {
    bf16x8 r;
    r[0] = f2bf(a.x); r[1] = f2bf(a.y); r[2] = f2bf(a.z); r[3] = f2bf(a.w);
    r[4] = f2bf(b.x); r[5] = f2bf(b.y); r[6] = f2bf(b.z); r[7] = f2bf(b.w);
    return r;
}

static __device__ __forceinline__ bf16x8 cvt8(const float* p) {
    return cvt8f(*(const float4*)p, *(const float4*)(p + 4));
}

// tanh(x) = 1 - 2/(exp(2x)+1)
static __device__ __forceinline__ float tanh_fast(float x) {
    float e = __expf(2.0f * x);
    return 1.0f - 2.0f * __builtin_amdgcn_rcpf(e + 1.0f);
}

static __device__ __forceinline__ float dot4(float4 a, float4 b) {
    return a.x * b.x + a.y * b.y + a.z * b.z + a.w * b.w;
}

#define MFMA16(a, b, c) __builtin_amdgcn_mfma_f32_16x16x32_bf16((a), (b), (c), 0, 0, 0)

// ---------------------------------------------------------------------------
// K0_stream: 8 threads per row (n,t,v).  Coalesced 16B in/out, no LDS.
//   xbf[n,t,v,c] bf16 ; m1g/m2g[n][k=(r*64+t)][v] f32.
// ---------------------------------------------------------------------------
__global__ __launch_bounds__(256) void k0_stream(
    const float* __restrict__ x,
    const float* __restrict__ w_m1, const float* __restrict__ b_m1,
    const float* __restrict__ w_m2, const float* __restrict__ b_m2,
    short* __restrict__ xbf, float* __restrict__ m1g, float* __restrict__ m2g)
{
    const int g  = blockIdx.x * 256 + threadIdx.x;   // 2M threads
    const int R  = g >> 3;                            // row id (n,t,v)
    const int l8 = g & 7;
    const int c0 = l8 * 8;
    const int n  = R >> 12, tt = (R >> 6) & 63, v = R & 63;

    const float* xp = x + ((size_t)R << 6) + c0;
    const float4 a0 = *(const float4*)xp;
    const float4 a1 = *(const float4*)(xp + 4);

    // partial dots over this thread's 8 channels
    float s0 = dot4(a0, *(const float4*)(w_m1 + c0))
             + dot4(a1, *(const float4*)(w_m1 + c0 + 4));
    float s1 = dot4(a0, *(const float4*)(w_m1 + 64 + c0))
             + dot4(a1, *(const float4*)(w_m1 + 64 + c0 + 4));
    float s2 = dot4(a0, *(const float4*)(w_m2 + c0))
             + dot4(a1, *(const float4*)(w_m2 + c0 + 4));
    float s3 = dot4(a0, *(const float4*)(w_m2 + 64 + c0))
             + dot4(a1, *(const float4*)(w_m2 + 64 + c0 + 4));

    // bf16 copy of x (coalesced 16B/lane)
    *(bf16x8*)(xbf + ((size_t)R << 6) + c0) = cvt8f(a0, a1);

    // reduce the 4 dots across the 8-lane group
#pragma unroll
    for (int m = 1; m < 8; m <<= 1) {
        s0 += __shfl_xor(s0, m);
        s1 += __shfl_xor(s1, m);
        s2 += __shfl_xor(s2, m);
        s3 += __shfl_xor(s3, m);
    }
    if (l8 < 4) {
        float s    = (l8 == 0) ? s0 : (l8 == 1) ? s1 : (l8 == 2) ? s2 : s3;
        float bias = (l8 < 2) ? b_m1[l8] : b_m2[l8 - 2];
        float* base = (l8 < 2) ? m1g : m2g;
        base[n * 8192 + ((l8 & 1) * 64 + tt) * 64 + v] = s + bias;
    }
}

// ---------------------------------------------------------------------------
// K1: block (n, i-chunk of 8), 512 thr.  adjf[n,t,i,j] bf16.  (R9 proven.)
// ---------------------------------------------------------------------------
__global__ __launch_bounds__(512) void k1_adj(
    const float* __restrict__ Ast,
    const float* __restrict__ w_rm, const float* __restrict__ b_rm,
    const float* __restrict__ m1g,  const float* __restrict__ m2g,
    const int* __restrict__ alpha_p,
    short* __restrict__ adjf)
{
    __shared__ float m2s[128 * 66];     // [k][j] stride 66  (33.8 KB)
    __shared__ float m1s[8 * 136];      // [iq][k]            (4.3 KB)

    const int wg = blockIdx.x;          // XCD swizzle: same-n -> same XCD
    const int n  = (wg & 7) + ((wg >> 6) << 3);
    const int i0 = ((wg >> 3) & 7) * 8;
    const int tid = threadIdx.x;

    {
        const float4* src2 = (const float4*)(m2g + n * 8192);
        for (int it = tid; it < 2048; it += 512) {
            int k = it >> 4, j0 = (it & 15) * 4;
            float4 v = src2[it];
            float* d = m2s + k * 66 + j0;
            *(float2*)d       = make_float2(v.x, v.y);
            *(float2*)(d + 2) = make_float2(v.z, v.w);
        }
    }
    if (tid < 256) {
        int k = tid & 127, half = tid >> 7;
        float4 v = *(const float4*)(m1g + n * 8192 + k * 64 + i0 + half * 4);
        m1s[(half * 4 + 0) * 136 + k] = v.x;
        m1s[(half * 4 + 1) * 136 + k] = v.y;
        m1s[(half * 4 + 2) * 136 + k] = v.z;
        m1s[(half * 4 + 3) * 136 + k] = v.w;
    }
    __syncthreads();

    const int l = tid & 63, w = tid >> 6;
    const int lr = l & 15, lg = l >> 4;
    const int ig = i0 + w;

    float alpha;
    {
        int raw = alpha_p[0];
        unsigned ur = (unsigned)(raw < 0 ? -raw : raw);
        alpha = (ur < (1u << 23)) ? (float)raw : __int_as_float(raw);
    }

    const float* m1row = m1s + w * 136;
    short* adjb = adjf + ((size_t)n << 18) + (ig << 6);

#pragma unroll 1
    for (int jt = 0; jt < 4; ++jt) {
        const int j = jt * 16 + lr;
        bf16x8 bfr[4];                  // transient tanh A-fragments
#pragma unroll
        for (int kt = 0; kt < 4; ++kt) {
            const int k0 = kt * 32 + lg * 8;
#pragma unroll
            for (int d = 0; d < 8; ++d)
                bfr[kt][d] = f2bf(tanh_fast(m1row[k0 + d] - m2s[(k0 + d) * 66 + j]));
        }
        const int j0 = jt * 16 + lg * 4;
#pragma unroll
        for (int q = 0; q < 4; ++q) {
            const int tq = q * 16 + lr;
            bf16x8 afq[4];              // transient w_rm B-fragments
#pragma unroll
            for (int kt = 0; kt < 4; ++kt)
                afq[kt] = cvt8(w_rm + tq * 128 + kt * 32 + lg * 8);
            f32x4 acc = (f32x4){0.f, 0.f, 0.f, 0.f};
#pragma unroll
            for (int kt = 0; kt < 4; ++kt)
                acc = MFMA16(bfr[kt], afq[kt], acc);            // D[j][t]
            float4 av = *(const float4*)(Ast + (tq << 12) + (ig << 6) + j0);
            float brm = b_rm[tq];
            bf16x4 pv;
            pv[0] = f2bf(alpha * (acc[0] + brm) + av.x);
            pv[1] = f2bf(alpha * (acc[1] + brm) + av.y);
            pv[2] = f2bf(alpha * (acc[2] + brm) + av.z);
            pv[3] = f2bf(alpha * (acc[3] + brm) + av.w);
            *(bf16x4*)(adjb + ((size_t)tq << 12) + j0) = pv;    // 8B store
        }
    }
}

// ---------------------------------------------------------------------------
// K2: block = one (n,t), 4 waves.
//   Phase1: P[i][c] = sum_j adj[i][j] x[j][c]  (wave w -> c-tile w;
//           wave 0 also computes P[i][64] = rowsum(adj) via ones-fragment)
//   Phase2: out[i][o] = sum_c P[i][c] Waug[o][c], Waug[o][64] = b_f[o].
// ---------------------------------------------------------------------------
__global__ __launch_bounds__(256) void k2_out(
    const short* __restrict__ adjf, const short* __restrict__ xbf,
    const float* __restrict__ w_f,  const float* __restrict__ b_f,
    float* __restrict__ out)
{
    __shared__ short xT[64 * 72];       // [c][j] bf16, stride 72   (9.2 KB)
    __shared__ short P[64 * 104];       // [i][c] bf16, stride 104 (13.3 KB)

    const int pair = blockIdx.x;        // n*64 + t
    const int tid  = threadIdx.x;
    const int l = tid & 63, w = tid >> 6;
    const int lr = l & 15, lg = l >> 4;

    const short* Ab = adjf + ((size_t)pair << 12);
    const short* Xb = xbf  + ((size_t)pair << 12);
    float*       Ob = out  + ((size_t)pair << 12);

    // ---- issue adj A-fragment loads early (global, 16B each)
    bf16x8 adjA[4][2];
#pragma unroll
    for (int mt = 0; mt < 4; ++mt)
#pragma unroll
        for (int ks = 0; ks < 2; ++ks)
            adjA[mt][ks] = *(const bf16x8*)(Ab + (mt * 16 + lr) * 64
                                            + ks * 32 + lg * 8);

    // ---- stage xT[c][j] from xbf[j][c]: thread -> (j = tid>>2, c0 = (tid&3)*16)
    {
        const int j  = tid >> 2;
        const int c0 = (tid & 3) * 16;
        bf16x8 r0 = *(const bf16x8*)(Xb + j * 64 + c0);
        bf16x8 r1 = *(const bf16x8*)(Xb + j * 64 + c0 + 8);
#pragma unroll
        for (int d = 0; d < 8; ++d) {
            xT[(c0 + d) * 72 + j]     = r0[d];
            xT[(c0 + 8 + d) * 72 + j] = r1[d];
        }
    }
    // ---- zero P cols 80..95 (cols 64..79 are written by wave 0's ones-tile)
    if (tid < 128) {
        int row = tid >> 1, cz = 80 + (tid & 1) * 8;
        bf16x8 z = {0, 0, 0, 0, 0, 0, 0, 0};
        *(bf16x8*)(P + row * 104 + cz) = z;
    }
    __syncthreads();

    // ---- Phase 1: wave w computes P c-tile w (c = w*16 + lr)
    {
        bf16x8 bx[2];
#pragma unroll
        for (int ks = 0; ks < 2; ++ks)
            bx[ks] = *(const bf16x8*)(xT + (w * 16 + lr) * 72 + ks * 32 + lg * 8);

        f32x4 acc[4];
#pragma unroll
        for (int mt = 0; mt < 4; ++mt) acc[mt] = (f32x4){0.f, 0.f, 0.f, 0.f};
#pragma unroll
        for (int ks = 0; ks < 2; ++ks)
#pragma unroll
            for (int mt = 0; mt < 4; ++mt)
                acc[mt] = MFMA16(adjA[mt][ks], bx[ks], acc[mt]);   // D[i][c]

#pragma unroll
        for (int mt = 0; mt < 4; ++mt)
#pragma unroll
            for (int e = 0; e < 4; ++e)
                P[(mt * 16 + lg * 4 + e) * 104 + w * 16 + lr] = f2bf(acc[mt][e]);

        if (w == 0) {                   // ones-tile -> P cols 64..79 (rowsum in 64)
            bf16x8 ones = {0, 0, 0, 0, 0, 0, 0, 0};
            if (lr == 0) {
#pragma unroll
                for (int d = 0; d < 8; ++d) ones[d] = (short)0x3F80;
            }
            f32x4 accO[4];
#pragma unroll
            for (int mt = 0; mt < 4; ++mt) accO[mt] = (f32x4){0.f, 0.f, 0.f, 0.f};
#pragma unroll
            for (int ks = 0; ks < 2; ++ks)
#pragma unroll
                for (int mt = 0; mt < 4; ++mt)
                    accO[mt] = MFMA16(adjA[mt][ks], ones, accO[mt]);
#pragma unroll
            for (int mt = 0; mt < 4; ++mt)
#pragma unroll
                for (int e = 0; e < 4; ++e)
                    P[(mt * 16 + lg * 4 + e) * 104 + 64 + lr] = f2bf(accO[mt][e]);
        }
    }
    __syncthreads();

    // ---- Phase 2: wave w -> o-tile w.  out = Waug @ P  (D[o][i])
    {
        const int o = w * 16 + lr;
        bf16x8 afw[3];
#pragma unroll
        for (int ks = 0; ks < 2; ++ks)
            afw[ks] = cvt8(w_f + o * 64 + ks * 32 + lg * 8);
        {
            bf16x8 ab = {0, 0, 0, 0, 0, 0, 0, 0};
            if (lg == 0) ab[0] = f2bf(b_f[o]);      // Waug[o][64] = b_f[o]
            afw[2] = ab;
        }

#pragma unroll
        for (int nt = 0; nt < 4; ++nt) {
            const int i = nt * 16 + lr;
            bf16x8 bP[3];
#pragma unroll
            for (int ks = 0; ks < 3; ++ks)
                bP[ks] = *(const bf16x8*)(P + i * 104 + ks * 32 + lg * 8);
            f32x4 acc = (f32x4){0.f, 0.f, 0.f, 0.f};
#pragma unroll
            for (int ks = 0; ks < 3; ++ks)
                acc = MFMA16(afw[ks], bP[ks], acc);             // D[o][i]
            *(f32x4*)(Ob + i * 64 + w * 16 + lg * 4) = acc;     // 16B store
        }
    }
}

// ---------------------------------------------------------------------------
extern "C" void kernel_launch(void* const* d_in, const int* in_sizes, int n_in,
                              void* d_out, int out_size, void* d_ws, size_t ws_size,
                              hipStream_t stream)
{
    const float* x    = (const float*)d_in[0];
    const float* A    = (const float*)d_in[1];
    const float* w_m1 = (const float*)d_in[2];
    const float* b_m1 = (const float*)d_in[3];
    const float* w_m2 = (const float*)d_in[4];
    const float* b_m2 = (const float*)d_in[5];
    const float* w_rm = (const float*)d_in[6];
    const float* b_rm = (const float*)d_in[7];
    const float* w_f  = (const float*)d_in[8];
    const float* b_f  = (const float*)d_in[9];
    const int*   alpha = (const int*)d_in[10];

    char* ws = (char*)d_ws;
    float* m1g = (float*)(ws);                              // 2 MB  [n][k][i]
    float* m2g = (float*)(ws + (size_t)2 * 1024 * 1024);    // 2 MB  [n][k][j]
    short* xbf = (short*)(ws + (size_t)4 * 1024 * 1024);    // 32 MB [n][t][v][c]
    short* adjf = (short*)(ws + (size_t)4 * 1024 * 1024 + (size_t)33554432);
    float* out = (float*)d_out;

    k0_stream<<<dim3(8192), dim3(256), 0, stream>>>(x, w_m1, b_m1, w_m2, b_m2,
                                                    xbf, m1g, m2g);
    k1_adj<<<dim3(512), dim3(512), 0, stream>>>(A, w_rm, b_rm, m1g, m2g,
                                                alpha, adjf);
    k2_out<<<dim3(4096), dim3(256), 0, stream>>>(adjf, xbf, w_f, b_f, out);
}